// Round 1
// baseline (8655.631 us; speedup 1.0000x reference)
//
#include <hip/hip_runtime.h>
#include <cmath>

// Problem dims (fixed at compile time for full alias/addressing optimization)
constexpr int Bv  = 64;
constexpr int T   = 512;
constexpr int KIN = 512;   // input dim == H here
constexpr int H   = 512;   // h_third
constexpr int OUTD = 256;
constexpr int M   = Bv * T;  // 32768 rows for the big GEMMs

// ---------------------------------------------------------------------------
// GEMM: C[M,N] = act(A[M,512] @ W[512,N] + b1[N] (+ b2[N]))   (fp32, K=512)
// 64x64 tile, 256 threads, 4x4 microtile per thread.
// ---------------------------------------------------------------------------
__global__ __launch_bounds__(256) void gemm_bias_act(
    const float* __restrict__ A, const float* __restrict__ W,
    const float* __restrict__ b1, const float* __restrict__ b2,
    float* __restrict__ C, int N, int do_tanh)
{
    constexpr int K = 512;
    __shared__ float As[16][64];   // [k][m] (transposed on store)
    __shared__ float Bs[16][64];   // [k][n]

    const int tid  = threadIdx.x;
    const int row0 = blockIdx.x * 64;
    const int col0 = blockIdx.y * 64;
    const int tx = tid & 15, ty = tid >> 4;        // 16x16 thread grid
    const int la_m = tid >> 2, la_k = (tid & 3) * 4;
    const int lb_k = tid >> 4, lb_n = (tid & 15) * 4;

    float acc[4][4] = {};

    const float* Aptr = A + (size_t)(row0 + la_m) * K + la_k;
    const float* Wptr = W + (size_t)lb_k * N + col0 + lb_n;

    for (int k0 = 0; k0 < K; k0 += 16) {
        const float4 a4 = *(const float4*)(Aptr + k0);
        const float4 b4 = *(const float4*)(Wptr + (size_t)k0 * N);
        As[la_k + 0][la_m] = a4.x;
        As[la_k + 1][la_m] = a4.y;
        As[la_k + 2][la_m] = a4.z;
        As[la_k + 3][la_m] = a4.w;
        *(float4*)&Bs[lb_k][lb_n] = b4;
        __syncthreads();
        #pragma unroll
        for (int k = 0; k < 16; ++k) {
            const float4 av = *(const float4*)&As[k][ty * 4];
            const float4 bv = *(const float4*)&Bs[k][tx * 4];
            acc[0][0] = fmaf(av.x, bv.x, acc[0][0]);
            acc[0][1] = fmaf(av.x, bv.y, acc[0][1]);
            acc[0][2] = fmaf(av.x, bv.z, acc[0][2]);
            acc[0][3] = fmaf(av.x, bv.w, acc[0][3]);
            acc[1][0] = fmaf(av.y, bv.x, acc[1][0]);
            acc[1][1] = fmaf(av.y, bv.y, acc[1][1]);
            acc[1][2] = fmaf(av.y, bv.z, acc[1][2]);
            acc[1][3] = fmaf(av.y, bv.w, acc[1][3]);
            acc[2][0] = fmaf(av.z, bv.x, acc[2][0]);
            acc[2][1] = fmaf(av.z, bv.y, acc[2][1]);
            acc[2][2] = fmaf(av.z, bv.z, acc[2][2]);
            acc[2][3] = fmaf(av.z, bv.w, acc[2][3]);
            acc[3][0] = fmaf(av.w, bv.x, acc[3][0]);
            acc[3][1] = fmaf(av.w, bv.y, acc[3][1]);
            acc[3][2] = fmaf(av.w, bv.z, acc[3][2]);
            acc[3][3] = fmaf(av.w, bv.w, acc[3][3]);
        }
        __syncthreads();
    }

    float4 bias = *(const float4*)&b1[col0 + tx * 4];
    if (b2 != nullptr) {
        const float4 e = *(const float4*)&b2[col0 + tx * 4];
        bias.x += e.x; bias.y += e.y; bias.z += e.z; bias.w += e.w;
    }
    #pragma unroll
    for (int i = 0; i < 4; ++i) {
        float4 v;
        v.x = acc[i][0] + bias.x;
        v.y = acc[i][1] + bias.y;
        v.z = acc[i][2] + bias.z;
        v.w = acc[i][3] + bias.w;
        if (do_tanh) {
            v.x = tanhf(v.x); v.y = tanhf(v.y); v.z = tanhf(v.z); v.w = tanhf(v.w);
        }
        *(float4*)&C[(size_t)(row0 + ty * 4 + i) * N + col0 + tx * 4] = v;
    }
}

// ---------------------------------------------------------------------------
// hs linear scan, in place: buf[b,t,h] holds tanh(x@Ws+bs) on entry, hs on exit.
// hs_t = (1-inv)*hs_{t-1} + inv*buf_t.   ILP over 4 batch rows per thread.
// ---------------------------------------------------------------------------
__global__ __launch_bounds__(256) void scan_hs_kernel(
    float* __restrict__ buf, const float* __restrict__ tau)
{
    const int h  = blockIdx.x * 256 + threadIdx.x;   // gridDim.x = 2
    const int b0 = blockIdx.y * 4;                   // gridDim.y = 16
    const float inv = 1.0f / tau[h];
    const float am  = 1.0f - inv;
    float s0 = 0.f, s1 = 0.f, s2 = 0.f, s3 = 0.f;
    const size_t bs_ = (size_t)T * H;
    const size_t i0 = (size_t)b0 * bs_ + h;
    for (int t = 0; t < T; ++t) {
        const size_t o = i0 + (size_t)t * H;
        const float x0 = buf[o];
        const float x1 = buf[o + bs_];
        const float x2 = buf[o + 2 * bs_];
        const float x3 = buf[o + 3 * bs_];
        s0 = am * s0 + inv * x0;
        s1 = am * s1 + inv * x1;
        s2 = am * s2 + inv * x2;
        s3 = am * s3 + inv * x3;
        buf[o]           = s0;
        buf[o + bs_]     = s1;
        buf[o + 2 * bs_] = s2;
        buf[o + 3 * bs_] = s3;
    }
}

// ---------------------------------------------------------------------------
// Nonlinear recurrence (one block per batch row, no grid sync):
//   h_t = (1-inv)*h_{t-1} + inv * tanh( U[b,t,:] + h_{t-1} @ Wr )
// 512 threads: tid = (ks<<7)|jg; thread computes cols [4*jg,4*jg+4) over
// k-slice [128*ks, 128*ks+128); 4 partials reduced via LDS; thread `tid`
// then owns state column `tid` for the update.
// ---------------------------------------------------------------------------
__global__ __launch_bounds__(512) void recur_kernel(
    const float* __restrict__ U, float* __restrict__ Hout,
    const float* __restrict__ Wr, const float* __restrict__ tau)
{
    __shared__ float h_lds[H];
    __shared__ float accb[4][H];

    const int b   = blockIdx.x;
    const int tid = threadIdx.x;
    const int jg  = tid & 127;
    const int ks  = tid >> 7;           // wave-uniform (2 waves per ks)
    const int j0  = jg * 4;
    const int kbase = ks * 128;

    const float inv = 1.0f / tau[tid];
    const float am  = 1.0f - inv;
    float h_reg = 0.0f;
    h_lds[tid] = 0.0f;
    __syncthreads();

    const float* __restrict__ Urow = U    + (size_t)b * T * H + tid;
    float* __restrict__       Hrow = Hout + (size_t)b * T * H + tid;

    for (int t = 0; t < T; ++t) {
        const float uval = Urow[(size_t)t * H];   // issue early, used in phase 2
        float4 acc = make_float4(0.f, 0.f, 0.f, 0.f);
        #pragma unroll 4
        for (int k = kbase; k < kbase + 128; k += 4) {
            const float4 h4 = *(const float4*)&h_lds[k];   // wave-uniform broadcast
            const float4 w0 = *(const float4*)&Wr[(size_t)(k + 0) * H + j0];
            const float4 w1 = *(const float4*)&Wr[(size_t)(k + 1) * H + j0];
            const float4 w2 = *(const float4*)&Wr[(size_t)(k + 2) * H + j0];
            const float4 w3 = *(const float4*)&Wr[(size_t)(k + 3) * H + j0];
            acc.x = fmaf(h4.x, w0.x, acc.x);
            acc.y = fmaf(h4.x, w0.y, acc.y);
            acc.z = fmaf(h4.x, w0.z, acc.z);
            acc.w = fmaf(h4.x, w0.w, acc.w);
            acc.x = fmaf(h4.y, w1.x, acc.x);
            acc.y = fmaf(h4.y, w1.y, acc.y);
            acc.z = fmaf(h4.y, w1.z, acc.z);
            acc.w = fmaf(h4.y, w1.w, acc.w);
            acc.x = fmaf(h4.z, w2.x, acc.x);
            acc.y = fmaf(h4.z, w2.y, acc.y);
            acc.z = fmaf(h4.z, w2.z, acc.z);
            acc.w = fmaf(h4.z, w2.w, acc.w);
            acc.x = fmaf(h4.w, w3.x, acc.x);
            acc.y = fmaf(h4.w, w3.y, acc.y);
            acc.z = fmaf(h4.w, w3.z, acc.z);
            acc.w = fmaf(h4.w, w3.w, acc.w);
        }
        *(float4*)&accb[ks][j0] = acc;
        __syncthreads();
        // phase 2: reduce partials + state update (thread tid owns column tid)
        const float a = accb[0][tid] + accb[1][tid] + accb[2][tid] + accb[3][tid] + uval;
        const float hnew = am * h_reg + inv * tanhf(a);
        h_reg = hnew;
        Hrow[(size_t)t * H] = hnew;
        h_lds[tid] = hnew;          // visible to next step's phase 1 after barrier
        __syncthreads();
    }
}

// ---------------------------------------------------------------------------
extern "C" void kernel_launch(void* const* d_in, const int* in_sizes, int n_in,
                              void* d_out, int out_size, void* d_ws, size_t ws_size,
                              hipStream_t stream)
{
    const float* x     = (const float*)d_in[0];
    const float* Ws    = (const float*)d_in[1];
    const float* bs    = (const float*)d_in[2];
    const float* Wi    = (const float*)d_in[3];
    const float* bi    = (const float*)d_in[4];
    const float* Wc    = (const float*)d_in[5];
    const float* bc    = (const float*)d_in[6];
    const float* Wm    = (const float*)d_in[7];
    const float* bm    = (const float*)d_in[8];
    const float* Wir   = (const float*)d_in[9];
    const float* bir   = (const float*)d_in[10];
    const float* Wcr   = (const float*)d_in[11];
    const float* bcr   = (const float*)d_in[12];
    const float* tau_s = (const float*)d_in[13];
    const float* tau_i = (const float*)d_in[14];
    const float* tau_c = (const float*)d_in[15];
    float* out = (float*)d_out;

    float* bufA = (float*)d_ws;                 // [B,T,H]  64 MB
    float* bufB = bufA + (size_t)M * H;         // [B,T,H]  64 MB

    const dim3 blk(256);

    // 1) bufA = tanh(x @ Ws + bs)                     [parallel GEMM]
    gemm_bias_act<<<dim3(M / 64, H / 64), blk, 0, stream>>>(x, Ws, bs, nullptr, bufA, H, 1);
    // 2) bufA = linear scan -> hs_all                 [parallel over B*H]
    scan_hs_kernel<<<dim3(H / 256, Bv / 4), blk, 0, stream>>>(bufA, tau_s);
    // 3) bufB = hs_all @ Wi + (bi + bir)              [parallel GEMM]
    gemm_bias_act<<<dim3(M / 64, H / 64), blk, 0, stream>>>(bufA, Wi, bi, bir, bufB, H, 0);
    // 4) bufA = hi_all  (serial over t, parallel over batch)
    recur_kernel<<<dim3(Bv), dim3(512), 0, stream>>>(bufB, bufA, Wir, tau_i);
    // 5) bufB = hi_all @ Wc + (bc + bcr)              [parallel GEMM]
    gemm_bias_act<<<dim3(M / 64, H / 64), blk, 0, stream>>>(bufA, Wc, bc, bcr, bufB, H, 0);
    // 6) bufA = hc_all
    recur_kernel<<<dim3(Bv), dim3(512), 0, stream>>>(bufB, bufA, Wcr, tau_c);
    // 7) out = hc_all @ Wm + bm                       [parallel GEMM]
    gemm_bias_act<<<dim3(M / 64, OUTD / 64), blk, 0, stream>>>(bufA, Wm, bm, nullptr, out, OUTD, 0);
}